// Round 7
// baseline (404.492 us; speedup 1.0000x reference)
//
#include <hip/hip_runtime.h>
#include <hip/hip_cooperative_groups.h>
#include <cfloat>
#include <cstdint>

namespace cg = cooperative_groups;
typedef unsigned int u32;

#define DSPLIT 4
#define ROWG 8

__device__ __forceinline__ void gload_lds16(const float* g, float* l) {
    __builtin_amdgcn_global_load_lds(
        (const __attribute__((address_space(1))) u32*)g,
        (__attribute__((address_space(3))) u32*)l, 16, 0, 0);
}

struct KParams {
    const float *boxes, *masks, *feat, *lang, *W_vs, *b_vs, *W_ts, *b_ts;
    const int* kptr;
    float *y_new, *z, *s_part;
    float *out_box, *out_mask, *out_max;
    int G, D, bs, AN, CH, CM, H;
};

struct Shared {
    union {
        struct { float A[32 * 34]; float B[32 * 36]; } g;          // gemm tiles
        struct { float4 buf[2][338]; float zs[256]; } f;           // feat stage
        struct { float ms[176]; int selg[176]; float simv[176];
                 float redw[4]; float bb; int sel[2]; } fin;
    } u;
};

// ---- 32x32-tile GEMM phase, KC=32, 2x2 microtile, reg-prefetch -------------
// BT=0: C[M,N] = A[M,K] @ B[K,N] (+bias). BT=1: B is [N,K] (C = A @ B^T).
template<int BT>
__device__ __forceinline__ void gemm_phase(
    Shared& sh, const float* __restrict__ A, const float* __restrict__ B,
    const float* __restrict__ bias, float* __restrict__ C,
    int M, int N, int K, int bid)
{
    float* Asm = sh.u.g.A;   // [kk][m], stride 34
    float* Bsm = sh.u.g.B;   // [kk][n], stride 36
    const int NB = N >> 5;
    int mi = bid / NB, ni = bid - mi * NB;
    int m0 = mi << 5, n0 = ni << 5;
    int t  = threadIdx.x;
    int rr = t >> 3, cc4 = (t & 7) << 2;
    int r2 = (t >> 4) << 1, c2 = (t & 15) << 1;
    float a00 = 0.f, a01 = 0.f, a10 = 0.f, a11 = 0.f;

    float4 ra, rb;
    ra = *(const float4*)&A[(size_t)(m0 + rr) * K + cc4];
    rb = BT ? *(const float4*)&B[(size_t)(n0 + rr) * K + cc4]
            : *(const float4*)&B[(size_t)rr * N + n0 + cc4];

    for (int k0 = 0; k0 < K; k0 += 32) {
        Asm[(cc4 + 0) * 34 + rr] = ra.x; Asm[(cc4 + 1) * 34 + rr] = ra.y;
        Asm[(cc4 + 2) * 34 + rr] = ra.z; Asm[(cc4 + 3) * 34 + rr] = ra.w;
        if (BT) {
            Bsm[(cc4 + 0) * 36 + rr] = rb.x; Bsm[(cc4 + 1) * 36 + rr] = rb.y;
            Bsm[(cc4 + 2) * 36 + rr] = rb.z; Bsm[(cc4 + 3) * 36 + rr] = rb.w;
        } else {
            *(float4*)&Bsm[rr * 36 + cc4] = rb;
        }
        __syncthreads();
        int kn = k0 + 32;
        if (kn < K) {
            ra = *(const float4*)&A[(size_t)(m0 + rr) * K + kn + cc4];
            rb = BT ? *(const float4*)&B[(size_t)(n0 + rr) * K + kn + cc4]
                    : *(const float4*)&B[(size_t)(kn + rr) * N + n0 + cc4];
        }
        #pragma unroll
        for (int kk = 0; kk < 32; kk++) {
            float2 a = *(const float2*)&Asm[kk * 34 + r2];
            float2 b = *(const float2*)&Bsm[kk * 36 + c2];
            a00 += a.x * b.x; a01 += a.x * b.y;
            a10 += a.y * b.x; a11 += a.y * b.y;
        }
        __syncthreads();
    }
    float bx = 0.f, by = 0.f;
    if (bias) { bx = bias[n0 + c2]; by = bias[n0 + c2 + 1]; }
    C[(size_t)(m0 + r2    ) * N + n0 + c2    ] = a00 + bx;
    C[(size_t)(m0 + r2    ) * N + n0 + c2 + 1] = a01 + by;
    C[(size_t)(m0 + r2 + 1) * N + n0 + c2    ] = a10 + bx;
    C[(size_t)(m0 + r2 + 1) * N + n0 + c2 + 1] = a11 + by;
}

// ---- feat.z partial: s_part[b,g,ds] over 256-d chunk, ROWG=8, dbuf DMA -----
__device__ __forceinline__ void feat_phase(const KParams& p, Shared& sh, int bid)
{
    const int b = bid >> 2, ds = bid & 3;
    const int G = p.G;                    // 169
    const int grpVec = 2 * G;             // 338 float4 per 8-row group
    int t  = threadIdx.x;
    int wb = t & ~63;

    sh.u.f.zs[t] = p.z[(size_t)b * p.D + ds * 256 + t];

    const float* gsrc = p.feat + ((size_t)b * p.D + (size_t)ds * 256) * G;
    {
        float* dst = (float*)sh.u.f.buf[0];
        gload_lds16(gsrc + 4 * t, dst + 4 * wb);
        if (t + 256 < grpVec)
            gload_lds16(gsrc + 4 * (t + 256), dst + 4 * (wb + 256));
    }
    __syncthreads();

    float acc = 0.f;
    int cur = 0;
    for (int gi = 0; gi < 32; gi++) {
        if (gi + 1 < 32) {
            const float* gs2 = gsrc + (size_t)(gi + 1) * (4 * grpVec);
            float* d2 = (float*)sh.u.f.buf[cur ^ 1];
            gload_lds16(gs2 + 4 * t, d2 + 4 * wb);
            if (t + 256 < grpVec)
                gload_lds16(gs2 + 4 * (t + 256), d2 + 4 * (wb + 256));
        }
        if (t < G) {
            const float* bp = (const float*)sh.u.f.buf[cur];
            #pragma unroll
            for (int r = 0; r < ROWG; r++)
                acc += bp[r * G + t] * sh.u.f.zs[gi * ROWG + r];
        }
        __syncthreads();
        cur ^= 1;
    }
    if (t < G) p.s_part[((size_t)b * G + t) * DSPLIT + ds] = acc;
}

// ---- per-batch finalize ----------------------------------------------------
__device__ __forceinline__ void fin_phase(const KParams& p, Shared& sh, int b)
{
    int t = threadIdx.x;
    int G = p.G, AN = p.AN, CH = p.CH, CM = p.CM, H = p.H;
    int k = *p.kptr; if (k > G) k = G;

    if (t < G) {
        const float* bp = p.boxes + (size_t)(b * G + t) * AN * CH;
        float s = 0.f;
        for (int a = 0; a < AN; a++) s += bp[a * CH + 4];
        sh.u.fin.ms[t] = s / (float)AN;
    }
    float part = 0.f;
    for (int h = t; h < H; h += 256)
        part += p.b_vs[h] * p.y_new[(size_t)b * H + h];
    #pragma unroll
    for (int off = 32; off > 0; off >>= 1) part += __shfl_down(part, off);
    if ((t & 63) == 0) sh.u.fin.redw[t >> 6] = part;
    __syncthreads();
    if (t == 0) sh.u.fin.bb = sh.u.fin.redw[0] + sh.u.fin.redw[1]
                            + sh.u.fin.redw[2] + sh.u.fin.redw[3];

    // exact top-k via rank (value desc, index asc) -- matches lax.top_k ties
    if (t < G) {
        float mv = sh.u.fin.ms[t];
        int rank = 0;
        for (int g = 0; g < G; g++) {
            float o = sh.u.fin.ms[g];
            rank += (int)((o > mv) | ((o == mv) & (g < t)));
        }
        if (rank < k) sh.u.fin.selg[rank] = t;
    }
    __syncthreads();

    if (t < k) {
        const float* sp = p.s_part + ((size_t)b * G + sh.u.fin.selg[t]) * DSPLIT;
        float s = 0.f;
        #pragma unroll
        for (int i = 0; i < DSPLIT; i++) s += sp[i];
        sh.u.fin.simv[t] = s;
    }
    __syncthreads();

    if (t == 0) {
        float best = -FLT_MAX; int br = 0;
        for (int r = 0; r < k; r++)
            if (sh.u.fin.simv[r] > best) { best = sh.u.fin.simv[r]; br = r; }
        int gs = sh.u.fin.selg[br];
        const float* bp = p.boxes + (size_t)(b * G + gs) * AN * CH;
        float bo = -FLT_MAX; int ai = 0;
        for (int a = 0; a < AN; a++) {
            float o = bp[a * CH + 4];
            if (o > bo) { bo = o; ai = a; }
        }
        float cx = bp[ai * CH + 0], cy = bp[ai * CH + 1];
        float w  = bp[ai * CH + 2], hh = bp[ai * CH + 3];
        float x1 = cx - w * 0.5f, y1 = cy - hh * 0.5f;
        p.out_box[(size_t)b * CH + 0] = x1;
        p.out_box[(size_t)b * CH + 1] = y1;
        p.out_box[(size_t)b * CH + 2] = x1 + w;
        p.out_box[(size_t)b * CH + 3] = y1 + hh;
        for (int c = 4; c < CH; c++) p.out_box[(size_t)b * CH + c] = bp[ai * CH + c];
        p.out_max[b] = best + sh.u.fin.bb;
        sh.u.fin.sel[0] = gs; sh.u.fin.sel[1] = ai;
    }
    __syncthreads();
    if (t < CM) {
        p.out_mask[(size_t)b * CM + t] =
            p.masks[((size_t)(b * G + sh.u.fin.sel[0]) * AN + sh.u.fin.sel[1]) * CM + t];
    }
}

// ---- cooperative all-in-one ------------------------------------------------
__global__ __launch_bounds__(256, 4) void coop_all(KParams p)
{
    __shared__ Shared sh;
    cg::grid_group grid = cg::this_grid();
    int bid = blockIdx.x;

    if (bid < 128) gemm_phase<0>(sh, p.lang, p.W_ts, p.b_ts, p.y_new, p.bs, p.H, p.H, bid);
    grid.sync();
    if (bid < 256) gemm_phase<1>(sh, p.y_new, p.W_vs, nullptr, p.z, p.bs, p.D, p.H, bid);
    grid.sync();
    feat_phase(p, sh, bid);
    grid.sync();
    if (bid < p.bs) fin_phase(p, sh, bid);
}

// ---- fallback wrappers (ordinary launches; graph edges provide ordering) ----
__global__ __launch_bounds__(256) void k_gemm1(KParams p) {
    __shared__ Shared sh;
    gemm_phase<0>(sh, p.lang, p.W_ts, p.b_ts, p.y_new, p.bs, p.H, p.H, blockIdx.x);
}
__global__ __launch_bounds__(256) void k_gemm2(KParams p) {
    __shared__ Shared sh;
    gemm_phase<1>(sh, p.y_new, p.W_vs, nullptr, p.z, p.bs, p.D, p.H, blockIdx.x);
}
__global__ __launch_bounds__(256) void k_feat(KParams p) {
    __shared__ Shared sh;
    feat_phase(p, sh, blockIdx.x);
}
__global__ __launch_bounds__(256) void k_fin(KParams p) {
    __shared__ Shared sh;
    fin_phase(p, sh, blockIdx.x);
}

extern "C" void kernel_launch(void* const* d_in, const int* in_sizes, int n_in,
                              void* d_out, int out_size, void* d_ws, size_t ws_size,
                              hipStream_t stream)
{
    KParams p;
    p.boxes = (const float*)d_in[0];
    p.masks = (const float*)d_in[1];
    p.feat  = (const float*)d_in[2];
    p.lang  = (const float*)d_in[3];
    p.W_vs  = (const float*)d_in[4];
    p.b_vs  = (const float*)d_in[5];
    p.W_ts  = (const float*)d_in[6];
    p.b_ts  = (const float*)d_in[7];
    p.kptr  = (const int*)d_in[8];

    p.H  = in_sizes[5];                      // 512
    p.D  = in_sizes[4] / p.H;                // 1024
    p.bs = in_sizes[3] / p.H;                // 256
    p.G  = in_sizes[2] / (p.bs * p.D);       // 169
    p.AN = 3;
    p.CH = in_sizes[0] / (p.bs * p.G * p.AN);// 5
    p.CM = in_sizes[1] / (p.bs * p.G * p.AN);// 32

    p.y_new  = (float*)d_ws;                              // bs*H
    p.z      = p.y_new + (size_t)p.bs * p.H;              // bs*D
    p.s_part = p.z + (size_t)p.bs * p.D;                  // bs*G*DSPLIT

    p.out_box  = (float*)d_out;
    p.out_mask = p.out_box + (size_t)p.bs * p.CH;
    p.out_max  = p.out_mask + (size_t)p.bs * p.CM;

    int nblk = p.bs * DSPLIT;                // 1024
    void* args[] = { (void*)&p };
    hipError_t e = hipLaunchCooperativeKernel(
        (const void*)coop_all, dim3(nblk), dim3(256), args, 0, stream);
    if (e != hipSuccess) {
        // fallback: same phases as ordinary kernels (graph edges order them)
        k_gemm1<<<128,  256, 0, stream>>>(p);
        k_gemm2<<<256,  256, 0, stream>>>(p);
        k_feat <<<nblk, 256, 0, stream>>>(p);
        k_fin  <<<p.bs, 256, 0, stream>>>(p);
    }
}

// Round 8
// 60.994 us; speedup vs baseline: 6.6317x; 6.6317x over previous
//
#include <hip/hip_runtime.h>
#include <cfloat>
#include <cstdint>

#define GBM 64
#define GBN 64
#define GBK 64
#define GPAD 68     // 68*4=272B rows: 16B-aligned for b128 frags

#define G_    169
#define D_    1024
#define SLAB  256   // feat rows per wave
#define ROWG  8     // rows per staged group
#define NGRP  32    // SLAB/ROWG
#define GRPF  1352  // ROWG*G_ floats per group
#define NV    338   // GRPF/4 float4 per group
#define SPL   8     // split-K slices

typedef unsigned int u32;

__device__ __forceinline__ void gload_lds16(const float* g, float* l) {
    __builtin_amdgcn_global_load_lds(
        (const __attribute__((address_space(1))) u32*)g,
        (__attribute__((address_space(3))) u32*)l, 16, 0, 0);
}

// stage one 8x169 group: 6 gload_lds16 instrs per wave (last partially masked)
__device__ __forceinline__ void stage_group(const float* gsrc, float* ldsbase, int lane) {
    #pragma unroll
    for (int j = 0; j < 6; j++) {
        int idx = j * 64 + lane;
        if (idx < NV)
            gload_lds16(gsrc + 4 * idx, ldsbase + j * 256);
    }
}

// ---- split-K GEMM: py[s][M][N] partial of A[M,K] @ B[K,N], one 64^3 tile/block
__global__ __launch_bounds__(256) void gemm_splitk(
    const float* __restrict__ A, const float* __restrict__ B,
    float* __restrict__ Cpart, int M, int N, int K)
{
    __shared__ __align__(16) float Asm[GBK][GPAD];  // [kk][m]
    __shared__ __align__(16) float Bsm[GBK][GPAD];  // [kk][n]
    int t  = threadIdx.x;
    int m0 = blockIdx.y * GBM, n0 = blockIdx.x * GBN;
    int ks = blockIdx.z * GBK;

    #pragma unroll
    for (int i = 0; i < 4; i++) {
        int v = t + 256 * i;
        int m = v >> 4, k4 = (v & 15) * 4;
        float4 x = *(const float4*)&A[(size_t)(m0 + m) * K + ks + k4];
        Asm[k4 + 0][m] = x.x; Asm[k4 + 1][m] = x.y;
        Asm[k4 + 2][m] = x.z; Asm[k4 + 3][m] = x.w;
    }
    #pragma unroll
    for (int i = 0; i < 4; i++) {
        int v = t + 256 * i;
        int r = v >> 4, c4 = (v & 15) * 4;
        *(float4*)&Bsm[r][c4] = *(const float4*)&B[(size_t)(ks + r) * N + n0 + c4];
    }
    __syncthreads();

    int r4 = (t >> 4) * 4, c4 = (t & 15) * 4;
    float acc[4][4] = {{0.f}};
    #pragma unroll
    for (int kk = 0; kk < GBK; kk++) {
        float4 a = *(const float4*)&Asm[kk][r4];
        float4 b = *(const float4*)&Bsm[kk][c4];
        float av[4] = {a.x, a.y, a.z, a.w};
        float bv[4] = {b.x, b.y, b.z, b.w};
        #pragma unroll
        for (int i = 0; i < 4; i++)
            #pragma unroll
            for (int j = 0; j < 4; j++) acc[i][j] += av[i] * bv[j];
    }
    float* Cp = Cpart + (size_t)blockIdx.z * M * N;
    #pragma unroll
    for (int i = 0; i < 4; i++) {
        float4 v = {acc[i][0], acc[i][1], acc[i][2], acc[i][3]};
        *(float4*)&Cp[(size_t)(m0 + r4 + i) * N + n0 + c4] = v;
    }
}

// ---- gemm2: pz[s][M][N] partial of (sum_s py + b_ts)[M,K] @ W[N,K]^T -------
// S-reduction fully unrolled -> 8 independent loads (R6 bug fix).
__global__ __launch_bounds__(256) void gemm2_fused(
    const float* __restrict__ py, const float* __restrict__ b_ts,
    const float* __restrict__ W, float* __restrict__ pz,
    int M, int N, int K)
{
    __shared__ __align__(16) float Asm[GBK][GPAD];  // [kk][m], kk = h in slice
    __shared__ __align__(16) float Bsm[GBK][GPAD];  // [kk][n]
    int t  = threadIdx.x;
    int m0 = blockIdx.y * GBM, n0 = blockIdx.x * GBN;
    int ks = blockIdx.z * GBK;

    #pragma unroll
    for (int i = 0; i < 4; i++) {                    // A = reduced y tile
        int v = t + 256 * i;
        int m = v >> 4, h4 = (v & 15) * 4;
        float4 x = *(const float4*)&b_ts[ks + h4];
        #pragma unroll
        for (int s = 0; s < SPL; s++) {              // 8 independent loads
            float4 p = *(const float4*)&py[((size_t)s * M + m0 + m) * K + ks + h4];
            x.x += p.x; x.y += p.y; x.z += p.z; x.w += p.w;
        }
        Asm[h4 + 0][m] = x.x; Asm[h4 + 1][m] = x.y;
        Asm[h4 + 2][m] = x.z; Asm[h4 + 3][m] = x.w;
    }
    #pragma unroll
    for (int i = 0; i < 4; i++) {                    // B^T tile
        int v = t + 256 * i;
        int n = v >> 4, k4 = (v & 15) * 4;
        float4 x = *(const float4*)&W[(size_t)(n0 + n) * K + ks + k4];
        Bsm[k4 + 0][n] = x.x; Bsm[k4 + 1][n] = x.y;
        Bsm[k4 + 2][n] = x.z; Bsm[k4 + 3][n] = x.w;
    }
    __syncthreads();

    int r4 = (t >> 4) * 4, c4 = (t & 15) * 4;
    float acc[4][4] = {{0.f}};
    #pragma unroll
    for (int kk = 0; kk < GBK; kk++) {
        float4 a = *(const float4*)&Asm[kk][r4];
        float4 b = *(const float4*)&Bsm[kk][c4];
        float av[4] = {a.x, a.y, a.z, a.w};
        float bv[4] = {b.x, b.y, b.z, b.w};
        #pragma unroll
        for (int i = 0; i < 4; i++)
            #pragma unroll
            for (int j = 0; j < 4; j++) acc[i][j] += av[i] * bv[j];
    }
    float* Cp = pz + (size_t)blockIdx.z * M * N;
    #pragma unroll
    for (int i = 0; i < 4; i++) {
        float4 v = {acc[i][0], acc[i][1], acc[i][2], acc[i][3]};
        *(float4*)&Cp[(size_t)(m0 + r4 + i) * N + n0 + c4] = v;
    }
}

// ---- feat.z for ALL grids of one batch + in-block finalize -----------------
// One block per batch. Per-wave DMA pipeline: each wave owns a 256-row slab,
// double-buffers 8-row groups via global_load_lds, ordered by counted
// s_waitcnt vmcnt(6) (never 0 mid-loop). No block barrier in the main loop.
__global__ __launch_bounds__(256) void feat_final(
    const float* __restrict__ feat, const float* __restrict__ pz,
    const float* __restrict__ boxes, const float* __restrict__ masks,
    const float* __restrict__ py, const float* __restrict__ b_ts,
    const float* __restrict__ b_vs, const int* __restrict__ kptr,
    float* __restrict__ out_box, float* __restrict__ out_mask,
    float* __restrict__ out_max,
    int bs, int AN, int CH, int CM, int H)
{
    __shared__ __align__(16) float buf[4][2][GRPF];   // per-wave dbuf
    __shared__ __align__(16) float zs[D_];
    __shared__ float accw[4 * 192];
    __shared__ float simall[176];
    __shared__ float ms[176];
    __shared__ int   selg[176];
    __shared__ float simv[176];
    __shared__ float redw[4];
    __shared__ float bbs;
    __shared__ int   selp[2];

    const int b = blockIdx.x;
    const int t = threadIdx.x;
    const int w = t >> 6, lane = t & 63;

    // z[b] = sum_s pz[s][b]; thread t covers zs[4t..4t+3] (same-wave region)
    {
        int h4 = t * 4;
        float4 s = {0.f, 0.f, 0.f, 0.f};
        #pragma unroll
        for (int sp = 0; sp < SPL; sp++) {
            float4 v = *(const float4*)&pz[((size_t)sp * bs + b) * D_ + h4];
            s.x += v.x; s.y += v.y; s.z += v.z; s.w += v.w;
        }
        *(float4*)&zs[h4] = s;   // wave w writes zs[w*256 .. +256) only
    }

    const float* gsrc = feat + ((size_t)b * D_ + (size_t)w * SLAB) * G_;
    stage_group(gsrc, buf[w][0], lane);

    float acc0 = 0.f, acc1 = 0.f, acc2 = 0.f;
    const bool g2 = lane < (G_ - 128);   // 41 lanes
    int cur = 0;
    for (int gi = 0; gi < NGRP; gi++) {
        if (gi + 1 < NGRP) {
            stage_group(gsrc + (size_t)(gi + 1) * GRPF, buf[w][cur ^ 1], lane);
            asm volatile("s_waitcnt vmcnt(6)" ::: "memory");   // group gi done
        } else {
            asm volatile("s_waitcnt vmcnt(0)" ::: "memory");
        }
        __builtin_amdgcn_sched_barrier(0);
        const float* bp = buf[w][cur];
        const float* zp = &zs[w * SLAB + gi * ROWG];
        #pragma unroll
        for (int r = 0; r < ROWG; r++) {
            float zv = zp[r];
            acc0 += bp[r * G_ + lane] * zv;
            acc1 += bp[r * G_ + lane + 64] * zv;
            if (g2) acc2 += bp[r * G_ + lane + 128] * zv;
        }
        cur ^= 1;
    }
    accw[w * 192 + lane]       = acc0;
    accw[w * 192 + lane + 64]  = acc1;
    if (g2) accw[w * 192 + lane + 128] = acc2;
    __syncthreads();

    // ---- finalize for batch b ----
    int k = *kptr; if (k > G_) k = G_;

    if (t < G_) {
        simall[t] = accw[t] + accw[192 + t] + accw[384 + t] + accw[576 + t];
        const float* bp = boxes + (size_t)(b * G_ + t) * AN * CH;
        float s = 0.f;
        for (int a = 0; a < AN; a++) s += bp[a * CH + 4];
        ms[t] = s / (float)AN;
    }
    // bb = b_vs . (sum_s py[s][b] + b_ts)
    float part = 0.f;
    for (int h = t; h < H; h += 256) {
        float yv = b_ts[h];
        #pragma unroll
        for (int s = 0; s < SPL; s++) yv += py[((size_t)s * bs + b) * H + h];
        part += b_vs[h] * yv;
    }
    #pragma unroll
    for (int off = 32; off > 0; off >>= 1) part += __shfl_down(part, off);
    if ((t & 63) == 0) redw[t >> 6] = part;
    __syncthreads();
    if (t == 0) bbs = redw[0] + redw[1] + redw[2] + redw[3];

    // exact top-k via rank (value desc, index asc) -- matches lax.top_k ties
    if (t < G_) {
        float mv = ms[t];
        int rank = 0;
        for (int g = 0; g < G_; g++) {
            float o = ms[g];
            rank += (int)((o > mv) | ((o == mv) & (g < t)));
        }
        if (rank < k) selg[rank] = t;
    }
    __syncthreads();

    if (t < k) simv[t] = simall[selg[t]];
    __syncthreads();

    if (t == 0) {
        float best = -FLT_MAX; int br = 0;
        for (int r = 0; r < k; r++) if (simv[r] > best) { best = simv[r]; br = r; }
        int gs = selg[br];
        const float* bp = boxes + (size_t)(b * G_ + gs) * AN * CH;
        float bo = -FLT_MAX; int ai = 0;
        for (int a = 0; a < AN; a++) { float o = bp[a * CH + 4]; if (o > bo) { bo = o; ai = a; } }
        float cx = bp[ai * CH + 0], cy = bp[ai * CH + 1];
        float ww = bp[ai * CH + 2], hh = bp[ai * CH + 3];
        float x1 = cx - ww * 0.5f, y1 = cy - hh * 0.5f;
        out_box[(size_t)b * CH + 0] = x1;
        out_box[(size_t)b * CH + 1] = y1;
        out_box[(size_t)b * CH + 2] = x1 + ww;
        out_box[(size_t)b * CH + 3] = y1 + hh;
        for (int c = 4; c < CH; c++) out_box[(size_t)b * CH + c] = bp[ai * CH + c];
        out_max[b] = best + bbs;
        selp[0] = gs; selp[1] = ai;
    }
    __syncthreads();
    if (t < CM) {
        out_mask[(size_t)b * CM + t] =
            masks[((size_t)(b * G_ + selp[0]) * AN + selp[1]) * CM + t];
    }
}

extern "C" void kernel_launch(void* const* d_in, const int* in_sizes, int n_in,
                              void* d_out, int out_size, void* d_ws, size_t ws_size,
                              hipStream_t stream)
{
    const float* boxes = (const float*)d_in[0];
    const float* masks = (const float*)d_in[1];
    const float* feat  = (const float*)d_in[2];
    const float* lang  = (const float*)d_in[3];
    const float* W_vs  = (const float*)d_in[4];
    const float* b_vs  = (const float*)d_in[5];
    const float* W_ts  = (const float*)d_in[6];
    const float* b_ts  = (const float*)d_in[7];
    const int*   kptr  = (const int*)d_in[8];

    int H  = in_sizes[5];                 // 512
    int D  = in_sizes[4] / H;             // 1024
    int bs = in_sizes[3] / H;             // 256
    int AN = 3;
    int CH = in_sizes[0] / (bs * G_ * AN); // 5
    int CM = in_sizes[1] / (bs * G_ * AN); // 32

    float* py = (float*)d_ws;                     // SPL*bs*H
    float* pz = py + (size_t)SPL * bs * H;        // SPL*bs*D

    float* out_box  = (float*)d_out;
    float* out_mask = out_box + (size_t)bs * CH;
    float* out_max  = out_mask + (size_t)bs * CM;

    // py = split-K partials of lang @ W_ts
    dim3 g1(H / GBN, bs / GBM, SPL);
    gemm_splitk<<<g1, 256, 0, stream>>>(lang, W_ts, py, bs, H, H);
    // pz = split-K partials of (sum py + b_ts) @ W_vs^T
    dim3 g2(D / GBN, bs / GBM, SPL);
    gemm2_fused<<<g2, 256, 0, stream>>>(py, b_ts, W_vs, pz, bs, D, H);
    // whole-batch feat.z + finalize, one block per batch
    feat_final<<<bs, 256, 0, stream>>>(feat, pz, boxes, masks, py, b_ts, b_vs,
                                       kptr, out_box, out_mask, out_max,
                                       bs, AN, CH, CM, H);
}

// Round 9
// 57.682 us; speedup vs baseline: 7.0125x; 1.0574x over previous
//
#include <hip/hip_runtime.h>
#include <cfloat>
#include <cstdint>

#define GBM 64
#define GBN 64
#define GBK 64
#define GPAD 68     // 68*4=272B rows: 16B-aligned for b128 frags

#define G_    169
#define D_    1024
#define NW    8     // waves per feat_final block (512 threads)
#define SLAB  128   // feat rows per wave
#define ROWG  8     // rows per staged group
#define NGRP  16    // SLAB/ROWG
#define GRPF  1352  // ROWG*G_ floats per group
#define NV    338   // GRPF/4 float4 per group
#define NBUF  3     // triple buffer -> 2-group lookahead
#define SPL   8     // split-K slices

typedef unsigned int u32;

__device__ __forceinline__ void gload_lds16(const float* g, float* l) {
    __builtin_amdgcn_global_load_lds(
        (const __attribute__((address_space(1))) u32*)g,
        (__attribute__((address_space(3))) u32*)l, 16, 0, 0);
}

// stage one 8x169 group: 6 gload_lds16 instrs per wave (last partially masked,
// still counts 1 vmcnt each -> constant 6/group)
__device__ __forceinline__ void stage_group(const float* gsrc, float* ldsbase, int lane) {
    #pragma unroll
    for (int j = 0; j < 6; j++) {
        int idx = j * 64 + lane;
        if (idx < NV)
            gload_lds16(gsrc + 4 * idx, ldsbase + j * 256);
    }
}

// ---- split-K GEMM: py[s][M][N] partial of A[M,K] @ B[K,N], one 64^3 tile/block
__global__ __launch_bounds__(256) void gemm_splitk(
    const float* __restrict__ A, const float* __restrict__ B,
    float* __restrict__ Cpart, int M, int N, int K)
{
    __shared__ __align__(16) float Asm[GBK][GPAD];  // [kk][m]
    __shared__ __align__(16) float Bsm[GBK][GPAD];  // [kk][n]
    int t  = threadIdx.x;
    int m0 = blockIdx.y * GBM, n0 = blockIdx.x * GBN;
    int ks = blockIdx.z * GBK;

    #pragma unroll
    for (int i = 0; i < 4; i++) {
        int v = t + 256 * i;
        int m = v >> 4, k4 = (v & 15) * 4;
        float4 x = *(const float4*)&A[(size_t)(m0 + m) * K + ks + k4];
        Asm[k4 + 0][m] = x.x; Asm[k4 + 1][m] = x.y;
        Asm[k4 + 2][m] = x.z; Asm[k4 + 3][m] = x.w;
    }
    #pragma unroll
    for (int i = 0; i < 4; i++) {
        int v = t + 256 * i;
        int r = v >> 4, c4 = (v & 15) * 4;
        *(float4*)&Bsm[r][c4] = *(const float4*)&B[(size_t)(ks + r) * N + n0 + c4];
    }
    __syncthreads();

    int r4 = (t >> 4) * 4, c4 = (t & 15) * 4;
    float acc[4][4] = {{0.f}};
    #pragma unroll
    for (int kk = 0; kk < GBK; kk++) {
        float4 a = *(const float4*)&Asm[kk][r4];
        float4 b = *(const float4*)&Bsm[kk][c4];
        float av[4] = {a.x, a.y, a.z, a.w};
        float bv[4] = {b.x, b.y, b.z, b.w};
        #pragma unroll
        for (int i = 0; i < 4; i++)
            #pragma unroll
            for (int j = 0; j < 4; j++) acc[i][j] += av[i] * bv[j];
    }
    float* Cp = Cpart + (size_t)blockIdx.z * M * N;
    #pragma unroll
    for (int i = 0; i < 4; i++) {
        float4 v = {acc[i][0], acc[i][1], acc[i][2], acc[i][3]};
        *(float4*)&Cp[(size_t)(m0 + r4 + i) * N + n0 + c4] = v;
    }
}

// ---- gemm2: pz[s][M][N] partial of (sum_s py + b_ts)[M,K] @ W[N,K]^T -------
__global__ __launch_bounds__(256) void gemm2_fused(
    const float* __restrict__ py, const float* __restrict__ b_ts,
    const float* __restrict__ W, float* __restrict__ pz,
    int M, int N, int K)
{
    __shared__ __align__(16) float Asm[GBK][GPAD];  // [kk][m], kk = h in slice
    __shared__ __align__(16) float Bsm[GBK][GPAD];  // [kk][n]
    int t  = threadIdx.x;
    int m0 = blockIdx.y * GBM, n0 = blockIdx.x * GBN;
    int ks = blockIdx.z * GBK;

    #pragma unroll
    for (int i = 0; i < 4; i++) {                    // A = reduced y tile
        int v = t + 256 * i;
        int m = v >> 4, h4 = (v & 15) * 4;
        float4 x = *(const float4*)&b_ts[ks + h4];
        #pragma unroll
        for (int s = 0; s < SPL; s++) {              // 8 independent loads
            float4 p = *(const float4*)&py[((size_t)s * M + m0 + m) * K + ks + h4];
            x.x += p.x; x.y += p.y; x.z += p.z; x.w += p.w;
        }
        Asm[h4 + 0][m] = x.x; Asm[h4 + 1][m] = x.y;
        Asm[h4 + 2][m] = x.z; Asm[h4 + 3][m] = x.w;
    }
    #pragma unroll
    for (int i = 0; i < 4; i++) {                    // B^T tile
        int v = t + 256 * i;
        int n = v >> 4, k4 = (v & 15) * 4;
        float4 x = *(const float4*)&W[(size_t)(n0 + n) * K + ks + k4];
        Bsm[k4 + 0][n] = x.x; Bsm[k4 + 1][n] = x.y;
        Bsm[k4 + 2][n] = x.z; Bsm[k4 + 3][n] = x.w;
    }
    __syncthreads();

    int r4 = (t >> 4) * 4, c4 = (t & 15) * 4;
    float acc[4][4] = {{0.f}};
    #pragma unroll
    for (int kk = 0; kk < GBK; kk++) {
        float4 a = *(const float4*)&Asm[kk][r4];
        float4 b = *(const float4*)&Bsm[kk][c4];
        float av[4] = {a.x, a.y, a.z, a.w};
        float bv[4] = {b.x, b.y, b.z, b.w};
        #pragma unroll
        for (int i = 0; i < 4; i++)
            #pragma unroll
            for (int j = 0; j < 4; j++) acc[i][j] += av[i] * bv[j];
    }
    float* Cp = pz + (size_t)blockIdx.z * M * N;
    #pragma unroll
    for (int i = 0; i < 4; i++) {
        float4 v = {acc[i][0], acc[i][1], acc[i][2], acc[i][3]};
        *(float4*)&Cp[(size_t)(m0 + r4 + i) * N + n0 + c4] = v;
    }
}

// ---- feat.z for ALL grids of one batch + in-block finalize -----------------
// One block per batch, 512 threads = 8 waves. Each wave owns a 128-row slab,
// triple-buffers 8-row groups via global_load_lds, ordered by counted
// s_waitcnt vmcnt(12/6/0) -- 2-group lookahead, no block barrier in main loop.
__global__ __launch_bounds__(512) void feat_final(
    const float* __restrict__ feat, const float* __restrict__ pz,
    const float* __restrict__ boxes, const float* __restrict__ masks,
    const float* __restrict__ py, const float* __restrict__ b_ts,
    const float* __restrict__ b_vs, const int* __restrict__ kptr,
    float* __restrict__ out_box, float* __restrict__ out_mask,
    float* __restrict__ out_max,
    int bs, int AN, int CH, int CM, int H)
{
    __shared__ __align__(16) float buf[NW][NBUF][GRPF];   // ~130 KB
    __shared__ __align__(16) float zs[D_];
    __shared__ float accw[NW * 192];
    __shared__ float simall[176];
    __shared__ float ms[176];
    __shared__ int   selg[176];
    __shared__ float simv[176];
    __shared__ float redw[NW];
    __shared__ float bbs;
    __shared__ int   selp[2];

    const int b = blockIdx.x;
    const int t = threadIdx.x;
    const int w = t >> 6, lane = t & 63;

    // z[b] = sum_s pz[s][b]; 512 threads x float2
    {
        int h2 = t * 2;
        float2 s = {0.f, 0.f};
        #pragma unroll
        for (int sp = 0; sp < SPL; sp++) {
            float2 v = *(const float2*)&pz[((size_t)sp * bs + b) * D_ + h2];
            s.x += v.x; s.y += v.y;
        }
        *(float2*)&zs[h2] = s;
    }
    __syncthreads();   // zs visible to all waves; drains pz loads (vmcnt=0)

    const float* gsrc = feat + ((size_t)b * D_ + (size_t)w * SLAB) * G_;
    stage_group(gsrc,        buf[w][0], lane);   // 6 outstanding
    stage_group(gsrc + GRPF, buf[w][1], lane);   // 12 outstanding

    float acc0 = 0.f, acc1 = 0.f, acc2 = 0.f;
    const bool g2 = lane < (G_ - 128);   // 41 lanes
    for (int gi = 0; gi < NGRP; gi++) {
        if (gi + 2 < NGRP) {
            stage_group(gsrc + (size_t)(gi + 2) * GRPF, buf[w][(gi + 2) % NBUF], lane);
            asm volatile("s_waitcnt vmcnt(12)" ::: "memory");   // group gi done
        } else if (gi + 1 < NGRP) {
            asm volatile("s_waitcnt vmcnt(6)" ::: "memory");
        } else {
            asm volatile("s_waitcnt vmcnt(0)" ::: "memory");
        }
        __builtin_amdgcn_sched_barrier(0);
        const float* bp = buf[w][gi % NBUF];
        const float* zp = &zs[w * SLAB + gi * ROWG];
        #pragma unroll
        for (int r = 0; r < ROWG; r++) {
            float zv = zp[r];
            acc0 += bp[r * G_ + lane] * zv;
            acc1 += bp[r * G_ + lane + 64] * zv;
            if (g2) acc2 += bp[r * G_ + lane + 128] * zv;
        }
    }
    accw[w * 192 + lane]       = acc0;
    accw[w * 192 + lane + 64]  = acc1;
    if (g2) accw[w * 192 + lane + 128] = acc2;
    __syncthreads();

    // ---- finalize for batch b ----
    int k = *kptr; if (k > G_) k = G_;

    if (t < G_) {
        float s = 0.f;
        #pragma unroll
        for (int ww = 0; ww < NW; ww++) s += accw[ww * 192 + t];
        simall[t] = s;
        const float* bp = boxes + (size_t)(b * G_ + t) * AN * CH;
        float o = 0.f;
        for (int a = 0; a < AN; a++) o += bp[a * CH + 4];
        ms[t] = o / (float)AN;
    }
    // bb = b_vs . (sum_s py[s][b] + b_ts); H == 512 == blockDim
    {
        float part = 0.f;
        for (int h = t; h < H; h += 512) {
            float yv = b_ts[h];
            #pragma unroll
            for (int s = 0; s < SPL; s++) yv += py[((size_t)s * bs + b) * H + h];
            part += b_vs[h] * yv;
        }
        #pragma unroll
        for (int off = 32; off > 0; off >>= 1) part += __shfl_down(part, off);
        if (lane == 0) redw[w] = part;
    }
    __syncthreads();
    if (t == 0) {
        float s = 0.f;
        #pragma unroll
        for (int ww = 0; ww < NW; ww++) s += redw[ww];
        bbs = s;
    }

    // exact top-k via rank (value desc, index asc) -- matches lax.top_k ties
    if (t < G_) {
        float mv = ms[t];
        int rank = 0;
        for (int g = 0; g < G_; g++) {
            float o = ms[g];
            rank += (int)((o > mv) | ((o == mv) & (g < t)));
        }
        if (rank < k) selg[rank] = t;
    }
    __syncthreads();

    if (t < k) simv[t] = simall[selg[t]];
    __syncthreads();

    if (t == 0) {
        float best = -FLT_MAX; int br = 0;
        for (int r = 0; r < k; r++) if (simv[r] > best) { best = simv[r]; br = r; }
        int gs = selg[br];
        const float* bp = boxes + (size_t)(b * G_ + gs) * AN * CH;
        float bo = -FLT_MAX; int ai = 0;
        for (int a = 0; a < AN; a++) { float o = bp[a * CH + 4]; if (o > bo) { bo = o; ai = a; } }
        float cx = bp[ai * CH + 0], cy = bp[ai * CH + 1];
        float ww = bp[ai * CH + 2], hh = bp[ai * CH + 3];
        float x1 = cx - ww * 0.5f, y1 = cy - hh * 0.5f;
        out_box[(size_t)b * CH + 0] = x1;
        out_box[(size_t)b * CH + 1] = y1;
        out_box[(size_t)b * CH + 2] = x1 + ww;
        out_box[(size_t)b * CH + 3] = y1 + hh;
        for (int c = 4; c < CH; c++) out_box[(size_t)b * CH + c] = bp[ai * CH + c];
        out_max[b] = best + bbs;
        selp[0] = gs; selp[1] = ai;
    }
    __syncthreads();
    if (t < CM) {
        out_mask[(size_t)b * CM + t] =
            masks[((size_t)(b * G_ + selp[0]) * AN + selp[1]) * CM + t];
    }
}

extern "C" void kernel_launch(void* const* d_in, const int* in_sizes, int n_in,
                              void* d_out, int out_size, void* d_ws, size_t ws_size,
                              hipStream_t stream)
{
    const float* boxes = (const float*)d_in[0];
    const float* masks = (const float*)d_in[1];
    const float* feat  = (const float*)d_in[2];
    const float* lang  = (const float*)d_in[3];
    const float* W_vs  = (const float*)d_in[4];
    const float* b_vs  = (const float*)d_in[5];
    const float* W_ts  = (const float*)d_in[6];
    const float* b_ts  = (const float*)d_in[7];
    const int*   kptr  = (const int*)d_in[8];

    int H  = in_sizes[5];                 // 512
    int D  = in_sizes[4] / H;             // 1024
    int bs = in_sizes[3] / H;             // 256
    int AN = 3;
    int CH = in_sizes[0] / (bs * G_ * AN); // 5
    int CM = in_sizes[1] / (bs * G_ * AN); // 32

    float* py = (float*)d_ws;                     // SPL*bs*H
    float* pz = py + (size_t)SPL * bs * H;        // SPL*bs*D

    float* out_box  = (float*)d_out;
    float* out_mask = out_box + (size_t)bs * CH;
    float* out_max  = out_mask + (size_t)bs * CM;

    // py = split-K partials of lang @ W_ts
    dim3 g1(H / GBN, bs / GBM, SPL);
    gemm_splitk<<<g1, 256, 0, stream>>>(lang, W_ts, py, bs, H, H);
    // pz = split-K partials of (sum py + b_ts) @ W_vs^T
    dim3 g2(D / GBN, bs / GBM, SPL);
    gemm2_fused<<<g2, 256, 0, stream>>>(py, b_ts, W_vs, pz, bs, D, H);
    // whole-batch feat.z + finalize, one block per batch, 8-wave pipeline
    feat_final<<<bs, 512, 0, stream>>>(feat, pz, boxes, masks, py, b_ts, b_vs,
                                       kptr, out_box, out_mask, out_max,
                                       bs, AN, CH, CM, H);
}